// Round 5
// baseline (117.728 us; speedup 1.0000x reference)
//
#include <hip/hip_runtime.h>
#include <hip/hip_bf16.h>

// QuantumKANLayer: S = [cos|sin features](32768x4096) @ W(4096x256), bf16 MFMA.
// R4: zero-LDS design. Each lane computes its A-fragment in registers via the
//     Chebyshev recurrence (one chain per (row,i); same recurrence for sin and
//     cos, init selected by lane-half). Wave = 32 rows x 64 cols -> one chain
//     feeds 2 MFMAs. No barriers, 4-deep B ring buffer from L2 (no spill).
//
// k-slot semantics (A and B must agree): for MFMA t at step s, k-slot
// h*8+e  <->  (h ? sin : cos)((e+1) * x[row][i]),  i = s*8 + t.

#define NST 32           // 4096 / 128

typedef __attribute__((ext_vector_type(8)))  short short8;
typedef __attribute__((ext_vector_type(16))) float f32x16;

static __device__ __forceinline__ unsigned short f2bf(float f) {
    union { float f; unsigned u; } v; v.f = f;
    unsigned r = v.u + 0x7fff + ((v.u >> 16) & 1);   // RNE
    return (unsigned short)(r >> 16);
}

// ---- pack W^T fragment-major for 32x32x16 B-frags -------------------------
// flat idx = ((s*8 + t)*8 + cg)*64 + l,  16B per idx.
// lane l: col j = cg*32 + (l&31), h = l>>5, i = s*8+t,
//         val[e] = (h ? coef_b : coef_a)[j][i][e]
__global__ __launch_bounds__(256) void pack_w_kernel(
        const float* __restrict__ ca, const float* __restrict__ cb,
        unsigned short* __restrict__ wt) {
    int idx = blockIdx.x * 256 + threadIdx.x;   // 131072
    int l  = idx & 63;
    int cg = (idx >> 6) & 7;
    int st = idx >> 9;                          // s*8 + t = i
    int j  = cg * 32 + (l & 31);
    const float* src = ((l >> 5) ? cb : ca) + ((size_t)j * 256 + st) * 8;
    float4 v0 = ((const float4*)src)[0];
    float4 v1 = ((const float4*)src)[1];
    alignas(16) unsigned short o[8];
    o[0] = f2bf(v0.x); o[1] = f2bf(v0.y); o[2] = f2bf(v0.z); o[3] = f2bf(v0.w);
    o[4] = f2bf(v1.x); o[5] = f2bf(v1.y); o[6] = f2bf(v1.z); o[7] = f2bf(v1.w);
    *(short8*)(wt + (size_t)idx * 8) = *(short8*)o;
}

// ---- fused feature-gen + GEMM, zero LDS -----------------------------------
// grid: 512 blocks = (rb 0..255) x (ch 0..1); block = 128 rows x 128 cols.
// 8 waves = 4(M) x 2(N); wave = rows rb*128+wm*32..+31, cols ch*128+wn*64..+63.
template<bool PACKED>
__global__ __launch_bounds__(512, 4) void kan_gemm(
        const float* __restrict__ x,
        const unsigned short* __restrict__ bwt,
        const float* __restrict__ ca, const float* __restrict__ cb,
        float* __restrict__ out) {
    const int tid   = threadIdx.x;
    const int l     = tid & 63;
    const int w     = tid >> 6;
    const int lrow  = l & 31;
    const int lhalf = l >> 5;
    const int wm    = w & 3;
    const int wn    = w >> 2;
    const int rb    = blockIdx.x >> 1;
    const int ch    = blockIdx.x & 1;

    const int row  = rb * 128 + wm * 32 + lrow;   // this lane's A row
    const int cg0  = ch * 4 + wn * 2;             // first of 2 col-groups

    f32x16 acc[2];
#pragma unroll
    for (int n = 0; n < 2; ++n)
#pragma unroll
        for (int r = 0; r < 16; ++r) acc[n][r] = 0.0f;

    const float* xp = x + (size_t)row * 256;
    const float p2init = lhalf ? 0.0f : 1.0f;

    auto loadB = [&](int s, int t, int cg) -> short8 {
        if (PACKED) {
            return ((const short8*)bwt)[(size_t)(((s * 8 + t) * 8 + cg) * 64 + l)];
        } else {
            const int j = cg * 32 + lrow;
            const int i = s * 8 + t;
            const float* src = (lhalf ? cb : ca) + ((size_t)j * 256 + i) * 8;
            float4 v0 = ((const float4*)src)[0];
            float4 v1 = ((const float4*)src)[1];
            alignas(16) unsigned short o[8];
            o[0] = f2bf(v0.x); o[1] = f2bf(v0.y);
            o[2] = f2bf(v0.z); o[3] = f2bf(v0.w);
            o[4] = f2bf(v1.x); o[5] = f2bf(v1.y);
            o[6] = f2bf(v1.z); o[7] = f2bf(v1.w);
            return *(short8*)o;
        }
    };

    // prologue: 4-deep B ring (per n), x for step 0
    short8 bq0[4], bq1[4];
#pragma unroll
    for (int j = 0; j < 4; ++j) {
        bq0[j] = loadB(0, j, cg0);
        bq1[j] = loadB(0, j, cg0 + 1);
    }
    float4 xa = *(const float4*)(xp + 0);
    float4 xb = *(const float4*)(xp + 4);

#pragma unroll 1
    for (int s = 0; s < NST; ++s) {
#pragma unroll
        for (int t = 0; t < 8; ++t) {
            // features for i = s*8+t: one Chebyshev chain, init by lane-half
            const float xv = (t < 4) ? xa[t] : xb[t - 4];
            float s1, c1;
            __sincosf(xv, &s1, &c1);
            float p1 = lhalf ? s1 : c1;
            float p2 = p2init;
            alignas(16) __hip_bfloat16 h[8];
            h[0] = __float2bfloat16(p1);
            const float tc = c1 + c1;
#pragma unroll
            for (int k = 1; k < 8; ++k) {
                const float pn = tc * p1 - p2;
                p2 = p1; p1 = pn;
                h[k] = __float2bfloat16(pn);
            }
            const short8 af = *(const short8*)h;

            __builtin_amdgcn_s_setprio(1);
            acc[0] = __builtin_amdgcn_mfma_f32_32x32x16_bf16(
                af, bq0[t & 3], acc[0], 0, 0, 0);
            acc[1] = __builtin_amdgcn_mfma_f32_32x32x16_bf16(
                af, bq1[t & 3], acc[1], 0, 0, 0);
            __builtin_amdgcn_s_setprio(0);

            // refill ring slot just consumed: data for (t+4) mod 8, 4 iters out
            const int sn = (t < 4) ? s : ((s + 1) & (NST - 1));
            const int tn = (t + 4) & 7;
            bq0[t & 3] = loadB(sn, tn, cg0);
            bq1[t & 3] = loadB(sn, tn, cg0 + 1);
            if (t == 3) xa = *(const float4*)(xp + (size_t)((s + 1) & (NST - 1)) * 8);
            if (t == 7) xb = *(const float4*)(xp + (size_t)((s + 1) & (NST - 1)) * 8 + 4);
        }
    }

    // epilogue: 32x32 C/D: col = lane&31, row = (r&3) + 8*(r>>2) + 4*lhalf
    const int colb = ch * 128 + wn * 64;
#pragma unroll
    for (int n = 0; n < 2; ++n)
#pragma unroll
        for (int r = 0; r < 16; ++r) {
            const int orow = rb * 128 + wm * 32 + (r & 3) + 8 * (r >> 2) + 4 * lhalf;
            out[(size_t)orow * 256 + colb + n * 32 + lrow] = acc[n][r];
        }
}

extern "C" void kernel_launch(void* const* d_in, const int* in_sizes, int n_in,
                              void* d_out, int out_size, void* d_ws, size_t ws_size,
                              hipStream_t stream) {
    const float* x  = (const float*)d_in[0];
    const float* ca = (const float*)d_in[1];
    const float* cb = (const float*)d_in[2];
    float* out = (float*)d_out;

    const size_t wt_bytes = (size_t)131072 * 16;   // 2 MiB

    if (ws_size >= wt_bytes) {
        unsigned short* wt = (unsigned short*)d_ws;
        pack_w_kernel<<<512, 256, 0, stream>>>(ca, cb, wt);
        kan_gemm<true><<<512, 512, 0, stream>>>(x, wt, ca, cb, out);
    } else {
        kan_gemm<false><<<512, 512, 0, stream>>>(x, nullptr, ca, cb, out);
    }
}